// Round 7
// baseline (462.151 us; speedup 1.0000x reference)
//
#include <hip/hip_runtime.h>

// CSConv2D: per-pixel kernel selection from a 25-entry 5x5 bank, depthwise,
// 'same' zero pad. B=8, C=96, H=W=192, fp32.
//
// R10: occupancy attack. R6-R9 evidence: only occupancy moved the needle
// (12->24 waves/CU: 99->78us); conv-core restructures at fixed occupancy
// were neutral (R8) or regressed (R9, latency chains). All pipes <40%,
// occupancy 30%, 0 bank conflicts -> latency/barrier-bound: 60KB LDS gave
// 2 blocks/CU = 2 barrier domains, so each phase barrier parked half the
// CU's waves.
//
// Fix: 64-col tiles, 256 threads, CPG=2, LDS = 2buf x 2ch x 12rows x 72
// floats + 2.5KB bank ~= 16.3KB -> 8 blocks/CU = 32 waves/CU (FULL) and 8
// independent barrier domains. Conv core is R8's verbatim (hoisted named-
// scalar weights, 77us best). Horizontal halo now staged (1.69x staging
// volume) but input fits L3 (113MB<256MB) so refetch is cache-absorbed.
//
// Edge-column staging (all 16B-aligned, never OOB):
//   cx=0: stage glob cols 0..67   (17 lanes) -> staged 4..71; cols 0..3 zero
//   cx=1: stage glob cols 60..131 (18 lanes) -> staged 0..71
//   cx=2: stage glob cols 124..191(17 lanes) -> staged 0..67; 68..71 zero
// Output col w (local) reads staged w+2..w+6 in all cases. Zero pads are
// written once and persist (staging never touches them).
//
// Per-wave VMEM ledger per phase: 6 loads then 4 stores -> s_waitcnt
// vmcnt(4) retires prior-phase stores + this phase's loads, leaves this
// phase's stores in flight.

#define KS 5
#define NB 25
#define HALO 2
#define TH 8                     // output rows per block
#define RPT 2                    // output rows per thread
#define CPG 2                    // channels per phase
#define TILE 64                  // output cols per block
#define WID 192
#define HEI 192
#define CH 96
#define NBATCH 8
#define LROW (TILE + 8)          // 72 staged floats per row
#define LH (TH + 2 * HALO)       // 12 staged rows
#define CSPLIT 4
#define CPB (CH / CSPLIT)        // 24 channels per block
#define NXT (WID / TILE)         // 3 col tiles
#define NTHREADS (TILE * (TH / RPT))  // 256 threads = 4 waves
#define HW ((size_t)HEI * WID)

static_assert(CPB % CPG == 0, "phase count integral");

__device__ __forceinline__ void async16(void* lds, const void* g) {
    // Direct global->LDS copy, 16B per lane. LDS dest is wave-uniform base +
    // lane*16 (hardware semantics); we pass the uniform row base.
    __builtin_amdgcn_global_load_lds(
        (const __attribute__((address_space(1))) void*)g,
        (__attribute__((address_space(3))) void*)lds, 16, 0, 0);
}

// ---- 50 named weight scalars: declaration, gather, FMA taps (R8 core) ----
#define WDECL(R)                                                              \
    float w##R##_0, w##R##_1, w##R##_2, w##R##_3, w##R##_4, w##R##_5,         \
        w##R##_6, w##R##_7, w##R##_8, w##R##_9, w##R##_10, w##R##_11,         \
        w##R##_12, w##R##_13, w##R##_14, w##R##_15, w##R##_16, w##R##_17,     \
        w##R##_18, w##R##_19, w##R##_20, w##R##_21, w##R##_22, w##R##_23,     \
        w##R##_24;

#define WGATH(R)                                                              \
    {                                                                         \
        const float* wp = &sb[bkt##R * (KS * KS)];                            \
        w##R##_0 = wp[0];   w##R##_1 = wp[1];   w##R##_2 = wp[2];             \
        w##R##_3 = wp[3];   w##R##_4 = wp[4];   w##R##_5 = wp[5];             \
        w##R##_6 = wp[6];   w##R##_7 = wp[7];   w##R##_8 = wp[8];             \
        w##R##_9 = wp[9];   w##R##_10 = wp[10]; w##R##_11 = wp[11];           \
        w##R##_12 = wp[12]; w##R##_13 = wp[13]; w##R##_14 = wp[14];           \
        w##R##_15 = wp[15]; w##R##_16 = wp[16]; w##R##_17 = wp[17];           \
        w##R##_18 = wp[18]; w##R##_19 = wp[19]; w##R##_20 = wp[20];           \
        w##R##_21 = wp[21]; w##R##_22 = wp[22]; w##R##_23 = wp[23];           \
        w##R##_24 = wp[24];                                                   \
    }

#define F5(R, T0, T1, T2, T3, T4)                                             \
    acc##R += x0 * w##R##_##T0 + x1 * w##R##_##T1 + x2 * w##R##_##T2          \
            + x3 * w##R##_##T3 + x4 * w##R##_##T4;

#define K0(R) F5(R, 0, 1, 2, 3, 4)
#define K1(R) F5(R, 5, 6, 7, 8, 9)
#define K2(R) F5(R, 10, 11, 12, 13, 14)
#define K3(R) F5(R, 15, 16, 17, 18, 19)
#define K4(R) F5(R, 20, 21, 22, 23, 24)

#define LOADX(CUR, SLAB, I)                                                   \
    {                                                                         \
        const float* rp = &sin_[CUR][SLAB][ty2 + (I)][xoff];                  \
        x0 = rp[0]; x1 = rp[1]; x2 = rp[2]; x3 = rp[3]; x4 = rp[4];           \
    }

#define CONV_STORE(CUR, SLAB, CIDX)                                           \
    {                                                                         \
        float acc0 = 0.0f, acc1 = 0.0f;                                       \
        float x0, x1, x2, x3, x4;                                             \
        LOADX(CUR, SLAB, 0) K0(0)                                             \
        LOADX(CUR, SLAB, 1) K1(0) K0(1)                                       \
        LOADX(CUR, SLAB, 2) K2(0) K1(1)                                       \
        LOADX(CUR, SLAB, 3) K3(0) K2(1)                                       \
        LOADX(CUR, SLAB, 4) K4(0) K3(1)                                       \
        LOADX(CUR, SLAB, 5) K4(1)                                             \
        float* op = outb + (size_t)(CIDX) * HW + (size_t)r0 * WID + gcol;     \
        op[0] = acc0; op[WID] = acc1;                                         \
    }

// Stage CPG channel slabs (base channel CBASE) into buffer BUF. 24 row-
// copies / 4 waves = 6 per wave; hg is wave-uniform (skip whole rows OOB).
#define STAGE(BUF, CBASE)                                                     \
    _Pragma("unroll")                                                         \
    for (int k = 0; k < 6; ++k) {                                             \
        const int m  = 6 * wv + k;        /* 0..23 */                         \
        const int s  = m / LH;            /* slab 0..1 */                     \
        const int rr = m % LH;            /* staged row 0..11 */              \
        const int hg = h0 - HALO + rr;                                        \
        if (hg >= 0 && hg < HEI && lane < nl)                                 \
            async16(&sin_[BUF][s][rr][dst0],                                  \
                    inb + (size_t)((CBASE) + s) * HW + (size_t)hg * WID       \
                        + src0 + lane * 4);                                   \
    }

__global__ __launch_bounds__(NTHREADS, 8) void csconv_kernel(
    const float* __restrict__ in, const float* __restrict__ bank,
    const int* __restrict__ buckets, float* __restrict__ out)
{
    __shared__ float sb[NB * KS * KS];                      // 2.5 KB bank
    __shared__ __align__(16) float sin_[2][CPG][LH][LROW];  // 13.5 KB slabs

    const int tid  = threadIdx.x;
    const int wcol = tid % TILE;    // 0..63 (local col)
    const int ty   = tid / TILE;    // 0..3 (row group)
    const int lane = tid & 63;
    const int wv   = tid >> 6;      // wave id 0..3
    const int bx   = blockIdx.x;    // 0..11
    const int cx   = bx % NXT;      // col tile 0..2
    const int cg   = bx / NXT;      // channel group 0..3
    const int ht   = blockIdx.y;    // row tile 0..23
    const int b    = blockIdx.z;    // batch 0..7
    const int h0   = ht * TH;
    const int r0   = h0 + ty * RPT; // first output row this thread owns
    const int gcol = cx * TILE + wcol;

    const int c0 = cg * CPB;
    const float* inb  = in  + (size_t)(b * CH + c0) * HW;
    float*       outb = out + (size_t)(b * CH + c0) * HW;

    // cx-dependent staging window (16B-aligned, in-bounds by construction).
    const int src0 = (cx == 0) ? 0 : (cx * TILE - 4);   // first staged col
    const int dst0 = (cx == 0) ? 4 : 0;                 // LDS float offset
    const int nl   = (cx == 1) ? 18 : 17;               // active lanes

    // --- one-time LDS init ---------------------------------------------
    for (int t = tid; t < NB * KS * KS; t += NTHREADS) sb[t] = bank[t];

    // Horizontal pad zeros (persist: staging never writes these cols).
    // cx=0: staged cols 0..3; cx=2: staged cols 68..71. 192 writes.
    if (cx != 1 && tid < 2 * CPG * LH * 4) {
        const int buf = tid / (CPG * LH * 4);
        const int s   = (tid / (LH * 4)) % CPG;
        const int r   = (tid / 4) % LH;
        const int p   = tid & 3;
        sin_[buf][s][r][(cx == 0 ? 0 : TILE + 4) + p] = 0.0f;
    }
    // Vertical OOB rows (edge row tiles): zero whole staged rows, persist.
    if (h0 - HALO < 0) {
        for (int t = tid; t < 2 * CPG * 2 * LROW; t += NTHREADS) {
            const int buf = t / (CPG * 2 * LROW);
            const int rem = t % (CPG * 2 * LROW);
            const int s   = rem / (2 * LROW);
            const int r   = (rem / LROW) % 2;       // rows 0,1
            sin_[buf][s][r][rem % LROW] = 0.0f;
        }
    }
    if (h0 + TH + HALO > HEI) {
        for (int t = tid; t < 2 * CPG * 2 * LROW; t += NTHREADS) {
            const int buf = t / (CPG * 2 * LROW);
            const int rem = t % (CPG * 2 * LROW);
            const int s   = rem / (2 * LROW);
            const int r   = (rem / LROW) % 2;       // rows 10,11
            sin_[buf][s][LH - 2 + r][rem % LROW] = 0.0f;
        }
    }

    // Prologue: stage channels 0..1 into buffer 0.
    STAGE(0, 0)

    __syncthreads();   // full drain once: bank, zeros, prologue copies

    // --- per-pixel weight gather: 2 buckets -> 50 named scalars (R8) -----
    const int bkt0 = buckets[(b * HEI + r0 + 0) * WID + gcol];
    const int bkt1 = buckets[(b * HEI + r0 + 1) * WID + gcol];
    WDECL(0) WDECL(1)
    WGATH(0) WGATH(1)

    const int ty2  = ty * RPT;
    const int xoff = wcol + 2;   // staged col of leftmost tap (all cx)

    // --- main loop: 12 phases of 2 channels --------------------------------
    for (int c = 0; c < CPB; c += CPG) {
        const int cur = (c / CPG) & 1;
        const bool has_next = (c + CPG < CPB);

        if (has_next) STAGE(cur ^ 1, c + CPG)

        CONV_STORE(cur, 0, c)
        CONV_STORE(cur, 1, c + 1)

        if (has_next) {
            // Per-wave order this phase: 6 loads, then 4 stores. vmcnt(4)
            // retires prior-phase stores + this phase's loads; this phase's
            // stores stay in flight across the barrier.
            asm volatile("s_waitcnt vmcnt(4)" ::: "memory");
            __builtin_amdgcn_s_barrier();
            asm volatile("" ::: "memory");
        }
    }
}

extern "C" void kernel_launch(void* const* d_in, const int* in_sizes, int n_in,
                              void* d_out, int out_size, void* d_ws, size_t ws_size,
                              hipStream_t stream) {
    const float* in      = (const float*)d_in[0];
    const float* bank    = (const float*)d_in[1];
    const int*   buckets = (const int*)d_in[2];
    float*       out     = (float*)d_out;
    dim3 grid(NXT * CSPLIT, HEI / TH, NBATCH);
    csconv_kernel<<<grid, NTHREADS, 0, stream>>>(in, bank, buckets, out);
}